// Round 20
// baseline (72.543 us; speedup 1.0000x reference)
//
#include <hip/hip_runtime.h>
#include <stdint.h>

#define NROWS 4096
#define DIM   512
#define EPS_W   1e-6f
#define NT    (NROWS / 128)        // 32 tiles per dim
#define NKS   (DIM / 64)           // 8 K-steps
#define NS    528                  // upper-triangle S tiles: 32*33/2

typedef unsigned short ushort_t;
typedef __attribute__((ext_vector_type(8))) short   short8;
typedef __attribute__((ext_vector_type(8))) unsigned short ushort8;
typedef __attribute__((ext_vector_type(4))) float   floatx4;
typedef __attribute__((ext_vector_type(4))) unsigned int uintx4;

// ---------- helpers ----------
__device__ inline ushort_t f2bf(float x) {            // RNE float->bf16
    unsigned u = __float_as_uint(x);
    unsigned r = (u + 0x7FFFu + ((u >> 16) & 1u)) >> 16;
    return (ushort_t)r;
}
__device__ inline float bf2f(ushort_t u) {
    return __uint_as_float(((unsigned)u) << 16);
}
// manual fp8 e4m3fn (OCP): RNE encode w/ clamp to 448, flush |x|<2^-6 to 0.
__device__ inline unsigned f2fp8(float x) {
    unsigned s = (__float_as_uint(x) >> 24) & 0x80u;
    float ax = fminf(fabsf(x), 448.0f);
    unsigned u = __float_as_uint(ax);
    unsigned r = u + 0x7FFFFu + ((u >> 20) & 1u);     // RNE at 3-bit mantissa
    unsigned b = s | (((r >> 23) - 120u) << 3) | ((r >> 20) & 7u);
    return (ax >= 0.015625f) ? b : s;                 // flush tiny to +-0
}
__device__ inline float fp82f(unsigned b) {
    unsigned em = b & 0x7Fu;
    float v = __uint_as_float(((b & 0x80u) << 24) | ((em << 20) + 0x3C000000u));
    return (em >= 8u) ? v : 0.0f;                     // encoder emits no subnormals
}
__device__ inline unsigned fmap(float f) {
    unsigned u = __float_as_uint(f);
    return (u & 0x80000000u) ? ~u : (u | 0x80000000u);
}
__device__ inline float funmap(unsigned u) {
    return __uint_as_float((u & 0x80000000u) ? (u & 0x7fffffffu) : ~u);
}

__device__ inline void gload_lds16(const void* g, void* l) {
    auto* gp = reinterpret_cast<const __attribute__((address_space(1))) unsigned int*>(
        reinterpret_cast<uintptr_t>(g));
    auto* lp = reinterpret_cast<__attribute__((address_space(3))) unsigned int*>(
        reinterpret_cast<uintptr_t>(l));
    __builtin_amdgcn_global_load_lds(gp, lp, 16, 0, 0);
}

// R1-verified 128x64 staging (0 bank conflicts). LDS[r][c_phys] holds logical
// chunk c_phys ^ (r&7) (chunk = 16B = 8 bf16).
__device__ inline void stage_tile(const ushort_t* __restrict__ gbase,
                                  ushort_t* lds, int wave, int lane) {
#pragma unroll
    for (int q = 0; q < 4; q++) {
        int row0 = wave * 32 + q * 8;
        int lrow = row0 + (lane >> 3);
        int src_chunk = (lane & 7) ^ (lane >> 3);
        const ushort_t* g = gbase + (size_t)lrow * DIM + src_chunk * 8;
        gload_lds16(g, lds + row0 * 64);
    }
}
__device__ inline short8 read_frag(const ushort_t* tile, int frag_row, int kk, int lane) {
    int r = frag_row * 16 + (lane & 15);
    int c = (kk * 4 + (lane >> 4)) ^ (lane & 7);
    return *reinterpret_cast<const short8*>(tile + r * 64 + c * 8);
}

// ---------- kernel 1: convert (raw T + normalized I,T) + init + out=0 ----------
__global__ __launch_bounds__(256) void prep_kernel(
    const float* __restrict__ img, const float* __restrict__ txt,
    ushort_t* __restrict__ Inrm, ushort_t* __restrict__ Traw,
    ushort_t* __restrict__ Tnrm,
    unsigned* __restrict__ mn_u, unsigned* __restrict__ mx_u,
    float* __restrict__ out) {
    const int wave = threadIdx.x >> 6, lane = threadIdx.x & 63;
    const int row = blockIdx.x * 4 + wave;
    const int col0 = lane * 8;
    if (blockIdx.x == 0 && threadIdx.x == 0) out[0] = 0.0f;  // replaces memset dispatch
    {
        const float4* p = reinterpret_cast<const float4*>(img + (size_t)row * DIM + col0);
        float4 a = p[0], b = p[1];
        float ss = a.x*a.x + a.y*a.y + a.z*a.z + a.w*a.w
                 + b.x*b.x + b.y*b.y + b.z*b.z + b.w*b.w;
#pragma unroll
        for (int s = 1; s < 64; s <<= 1) ss += __shfl_xor(ss, s);
        float rin = rsqrtf(ss);
        ushort8 o;
        o[0]=f2bf(a.x*rin); o[1]=f2bf(a.y*rin); o[2]=f2bf(a.z*rin); o[3]=f2bf(a.w*rin);
        o[4]=f2bf(b.x*rin); o[5]=f2bf(b.y*rin); o[6]=f2bf(b.z*rin); o[7]=f2bf(b.w*rin);
        *reinterpret_cast<ushort8*>(Inrm + (size_t)row * DIM + col0) = o;
    }
    {
        const float4* p = reinterpret_cast<const float4*>(txt + (size_t)row * DIM + col0);
        float4 a = p[0], b = p[1];
        float ss = a.x*a.x + a.y*a.y + a.z*a.z + a.w*a.w
                 + b.x*b.x + b.y*b.y + b.z*b.z + b.w*b.w;
#pragma unroll
        for (int s = 1; s < 64; s <<= 1) ss += __shfl_xor(ss, s);
        float rtn = rsqrtf(ss);
        ushort8 r8, n8;
        r8[0]=f2bf(a.x); r8[1]=f2bf(a.y); r8[2]=f2bf(a.z); r8[3]=f2bf(a.w);
        r8[4]=f2bf(b.x); r8[5]=f2bf(b.y); r8[6]=f2bf(b.z); r8[7]=f2bf(b.w);
        n8[0]=f2bf(a.x*rtn); n8[1]=f2bf(a.y*rtn); n8[2]=f2bf(a.z*rtn); n8[3]=f2bf(a.w*rtn);
        n8[4]=f2bf(b.x*rtn); n8[5]=f2bf(b.y*rtn); n8[6]=f2bf(b.z*rtn); n8[7]=f2bf(b.w*rtn);
        *reinterpret_cast<ushort8*>(Traw + (size_t)row * DIM + col0) = r8;
        *reinterpret_cast<ushort8*>(Tnrm + (size_t)row * DIM + col0) = n8;
    }
    if (lane == 0) { mn_u[row] = 0xFFFFFFFFu; mx_u[row] = 0u; }
}

// ---------- kernel 2: fused S/D GEMM, 2-phase dbuf + S-symmetry; fp8 outputs ----------
// Grid (SONLY=0): NS + 1024. bid < NS -> S tile (upper tri, ti <= tj); else D.
// S store: fp8 e4m3 sim; D store: fp8 e4m3 of cos*64. Both: wave-slot 4 KB,
// chunk f=m holds uint n (bytes = regs 0..3).
template <int SONLY>
__global__ __launch_bounds__(256) void gemm_kernel(
    const ushort_t* __restrict__ Traw, const ushort_t* __restrict__ Inrm,
    const ushort_t* __restrict__ Tnrm,
    unsigned* __restrict__ mn_u, unsigned* __restrict__ mx_u,
    unsigned char* __restrict__ simb, unsigned char* __restrict__ dotb) {
    __shared__ __align__(16) ushort_t LB[32768];     // 64 KB: Ta0|Ta1|Tb0|Tb1, reused
    ushort_t* TaB = LB;
    ushort_t* TbB = LB + 16384;
    int type, ti, tj;
    if (SONLY) {
        type = 0; ti = (int)blockIdx.x >> 5; tj = (int)blockIdx.x & 31;
    } else {
        int bid = (int)blockIdx.x;
        if (bid < NS) {                              // S: upper-triangle decode
            type = 0;
            int u = bid;
            int t = (int)(32.5f - sqrtf(32.5f * 32.5f - 2.0f * (float)u));
            int off = 32 * t - (t * (t - 1)) / 2;
            if (off > u) { t--; off = 32 * t - (t * (t - 1)) / 2; }
            else if (off + (32 - t) <= u) { off += (32 - t); t++; }
            ti = t; tj = t + (u - off);
        } else {
            type = 1; int v = bid - NS; ti = v >> 5; tj = v & 31;
        }
    }
    const int wave = threadIdx.x >> 6, lane = threadIdx.x & 63;
    const int wr = wave >> 1, wc = wave & 1;
    const ushort_t* gA = (type ? Inrm : Traw) + (size_t)(ti * 128) * DIM;
    const ushort_t* gB = (type ? Tnrm : Traw) + (size_t)(tj * 128) * DIM;

    floatx4 acc[4][4];
#pragma unroll
    for (int m = 0; m < 4; m++)
#pragma unroll
        for (int n = 0; n < 4; n++) acc[m][n] = (floatx4){0.f, 0.f, 0.f, 0.f};

    // 2-phase: issue next-step stage FIRST, compute current, one sync per step
    stage_tile(gA, TaB, wave, lane);
    stage_tile(gB, TbB, wave, lane);
    __syncthreads();
#pragma unroll
    for (int t = 0; t < NKS; t++) {
        if (t + 1 < NKS) {
            stage_tile(gA + (t + 1) * 64, TaB + ((t + 1) & 1) * 8192, wave, lane);
            stage_tile(gB + (t + 1) * 64, TbB + ((t + 1) & 1) * 8192, wave, lane);
        }
#pragma unroll
        for (int kk = 0; kk < 2; kk++) {
            short8 a[4], b[4];
#pragma unroll
            for (int m = 0; m < 4; m++) a[m] = read_frag(TaB + (t & 1) * 8192, wr * 4 + m, kk, lane);
#pragma unroll
            for (int n = 0; n < 4; n++) b[n] = read_frag(TbB + (t & 1) * 8192, wc * 4 + n, kk, lane);
#pragma unroll
            for (int m = 0; m < 4; m++)
#pragma unroll
                for (int n = 0; n < 4; n++)
                    acc[m][n] = __builtin_amdgcn_mfma_f32_16x16x32_bf16(a[m], b[n], acc[m][n], 0, 0, 0);
        }
        __syncthreads();
    }

    if (type == 0) {
        // row-axis min/max (fp32-exact, unaffected by fp8 sim store)
#pragma unroll
        for (int m = 0; m < 4; m++) {
#pragma unroll
            for (int reg = 0; reg < 4; reg++) {
                float vmin = acc[m][0][reg], vmax = acc[m][0][reg];
#pragma unroll
                for (int n = 1; n < 4; n++) {
                    vmin = fminf(vmin, acc[m][n][reg]);
                    vmax = fmaxf(vmax, acc[m][n][reg]);
                }
#pragma unroll
                for (int s = 1; s < 16; s <<= 1) {
                    vmin = fminf(vmin, __shfl_xor(vmin, s));
                    vmax = fmaxf(vmax, __shfl_xor(vmax, s));
                }
                if ((lane & 15) == 0) {
                    int row_g = ti * 128 + wr * 64 + m * 16 + (lane >> 4) * 4 + reg;
                    atomicMin(&mn_u[row_g], fmap(vmin));
                    atomicMax(&mx_u[row_g], fmap(vmax));
                }
            }
        }
        if (!SONLY && ti != tj) {
            // col-axis min/max -> rows of tj block by symmetry
#pragma unroll
            for (int n = 0; n < 4; n++) {
                float cmin = acc[0][n][0], cmax = acc[0][n][0];
#pragma unroll
                for (int m = 0; m < 4; m++)
#pragma unroll
                    for (int reg = 0; reg < 4; reg++) {
                        float v = acc[m][n][reg];
                        cmin = fminf(cmin, v); cmax = fmaxf(cmax, v);
                    }
                cmin = fminf(cmin, __shfl_xor(cmin, 16));
                cmax = fmaxf(cmax, __shfl_xor(cmax, 16));
                cmin = fminf(cmin, __shfl_xor(cmin, 32));
                cmax = fmaxf(cmax, __shfl_xor(cmax, 32));
                if ((lane >> 4) == 0) {
                    int row_g = tj * 128 + wc * 64 + n * 16 + lane;
                    atomicMin(&mn_u[row_g], fmap(cmin));
                    atomicMax(&mx_u[row_g], fmap(cmax));
                }
            }
        }
        // packed fp8 sim store at (ti,tj): chunk f=m, uint n = regs 0..3 (bytes)
        unsigned char* spb = simb + ((size_t)((ti * NT + tj) * 4 + wave)) * 4096;
#pragma unroll
        for (int f = 0; f < 4; f++) {
            uintx4 q;
#pragma unroll
            for (int n = 0; n < 4; n++)
                q[n] = f2fp8(acc[f][n][0])
                     | (f2fp8(acc[f][n][1]) << 8)
                     | (f2fp8(acc[f][n][2]) << 16)
                     | (f2fp8(acc[f][n][3]) << 24);
            *reinterpret_cast<uintx4*>(spb + f * 1024 + lane * 16) = q;
        }
        // transposed fp8 store at (tj,ti) via byte LDS bounce
        if (!SONLY && ti != tj) {
            unsigned char* LBb = reinterpret_cast<unsigned char*>(LB);
            const int rb0 = wr * 64, cb0 = wc * 64;
            const int l4 = lane >> 4, l15 = lane & 15;
#pragma unroll
            for (int m = 0; m < 4; m++)
#pragma unroll
                for (int n = 0; n < 4; n++)
#pragma unroll
                    for (int reg = 0; reg < 4; reg++)
                        LBb[(rb0 + m * 16 + l4 * 4 + reg) * 132 + (cb0 + n * 16 + l15)]
                            = (unsigned char)f2fp8(acc[m][n][reg]);
            __syncthreads();
            unsigned char* sp2 = simb + ((size_t)((tj * NT + ti) * 4 + wave)) * 4096;
#pragma unroll
            for (int f2 = 0; f2 < 4; f2++) {
                int row2b = (wave >> 1) * 64 + f2 * 16 + l4 * 4;       // mult of 4
                uintx4 q;
#pragma unroll
                for (int n2 = 0; n2 < 4; n2++) {
                    int col2 = (wave & 1) * 64 + n2 * 16 + l15;
                    q[n2] = *reinterpret_cast<const unsigned*>(&LBb[col2 * 132 + row2b]);
                }
                *reinterpret_cast<uintx4*>(sp2 + f2 * 1024 + lane * 16) = q;
            }
        }
    } else {
        // D: packed fp8 store of cos*64 (scale keeps typical cos in normal range)
        unsigned char* spb = dotb + ((size_t)((ti * NT + tj) * 4 + wave)) * 4096;
#pragma unroll
        for (int f = 0; f < 4; f++) {
            uintx4 q;
#pragma unroll
            for (int n = 0; n < 4; n++)
                q[n] = f2fp8(acc[f][n][0] * 64.0f)
                     | (f2fp8(acc[f][n][1] * 64.0f) << 8)
                     | (f2fp8(acc[f][n][2] * 64.0f) << 16)
                     | (f2fp8(acc[f][n][3] * 64.0f) << 24);
            *reinterpret_cast<uintx4*>(spb + f * 1024 + lane * 16) = q;
        }
    }
}

// ---------- kernel 3 (fallback path only): per-row params ----------
__global__ __launch_bounds__(256) void params_kernel(
    const unsigned* __restrict__ mn_u, const unsigned* __restrict__ mx_u,
    float2* __restrict__ params2) {
    int i = blockIdx.x * 256 + threadIdx.x;
    float mn = funmap(mn_u[i]), mx = funmap(mx_u[i]);
    params2[i] = make_float2(mn, 1.0f / (mx - mn + EPS_W));
}

// ---------- kernel 4: streaming loss; fp8 sim + fp8 dot, params in LDS ----------
// lane-chunk16 id g = t + k*2^17, k in [0,8): wslot = g>>8, f = (g>>6)&3,
// ln = g&63. k-invariant: f, ln, wave, tj; ti = ti0 + 4k. Per k: one 16B fp8
// sim + one 16B fp8 dot (16 pairs). 32 MB total (was 48).
__global__ __launch_bounds__(256) void loss_kernel(
    const unsigned char* __restrict__ simb, const unsigned char* __restrict__ dotb,
    const unsigned* __restrict__ mn_u, const unsigned* __restrict__ mx_u,
    const int* __restrict__ instr, float* __restrict__ out) {
    __shared__ __align__(16) float2 P[NROWS];            // 32 KB
    __shared__ float red[4];
    const int t = blockIdx.x * 256 + threadIdx.x;        // 0..131071
    const int rem = t & 255;
    const int f = rem >> 6, ln = rem & 63;
    const int wslot0 = t >> 8;                           // + 512k
    const int wv0 = wslot0 & 3;
    const int tile0 = wslot0 >> 2;                       // + 128k
    const int tj = tile0 & 31;
    const int ti0 = tile0 >> 5;                          // ti = ti0 + 4k

    uintx4 sv[8], dv[8];
#pragma unroll
    for (int k = 0; k < 8; k++) {
        size_t ws = (size_t)(wslot0 + k * 512);
        sv[k] = __builtin_nontemporal_load(
            reinterpret_cast<const uintx4*>(simb + ws * 4096 + f * 1024 + ln * 16));
        dv[k] = __builtin_nontemporal_load(
            reinterpret_cast<const uintx4*>(dotb + ws * 4096 + f * 1024 + ln * 16));
    }
    // params into LDS (16 rows/thread, coalesced; divides hide under loads)
#pragma unroll
    for (int q = 0; q < 16; q++) {
        int i = threadIdx.x + q * 256;
        float mn = funmap(mn_u[i]), mx = funmap(mx_u[i]);
        P[i] = make_float2(mn, 1.0f / (mx - mn + EPS_W));
    }
    __syncthreads();
    const int rb_lo = (wv0 >> 1) * 64 + f * 16 + (ln >> 4) * 4;
    const int cb = tj * 128 + (wv0 & 1) * 64 + (ln & 15);
    int icn[4], coln[4];
#pragma unroll
    for (int n = 0; n < 4; n++) { coln[n] = cb + n * 16; icn[n] = instr[coln[n]]; }

    float lsum = 0.f;
#pragma unroll
    for (int k = 0; k < 8; k++) {
        int rb = (ti0 + 4 * k) * 128 + rb_lo;            // %4 == 0
        float4 pA = *reinterpret_cast<const float4*>(&P[rb]);      // mn0,w0,mn1,w1
        float4 pB = *reinterpret_cast<const float4*>(&P[rb + 2]);  // mn2,w2,mn3,w3
        int4  ir4 = *reinterpret_cast<const int4*>(instr + rb);
#pragma unroll
        for (int n = 0; n < 4; n++) {
            unsigned qs = sv[k][n], qd = dv[k][n];
#pragma unroll
            for (int reg = 0; reg < 4; reg++) {
                float mn, wvv; int ir;
                if (reg == 0)      { mn = pA.x; wvv = pA.y; ir = ir4.x; }
                else if (reg == 1) { mn = pA.z; wvv = pA.w; ir = ir4.y; }
                else if (reg == 2) { mn = pB.x; wvv = pB.y; ir = ir4.z; }
                else               { mn = pB.z; wvv = pB.w; ir = ir4.w; }
                float simv = fp82f((qs >> (8 * reg)) & 0xFFu);
                float cosv = fp82f((qd >> (8 * reg)) & 0xFFu) * 0.015625f;
                float w = (simv - mn) * wvv;
                bool aligned = (ir == icn[n]) || (rb + reg == coln[n]);
                lsum += aligned ? (1.0f - cosv) : fmaxf(0.0f, cosv - w);
            }
        }
    }
#pragma unroll
    for (int s = 1; s < 64; s <<= 1) lsum += __shfl_xor(lsum, s);
    const int wave = threadIdx.x >> 6, lane = threadIdx.x & 63;
    if (lane == 0) red[wave] = lsum;
    __syncthreads();
    if (threadIdx.x == 0) {
        float v = red[0] + red[1] + red[2] + red[3];
        atomicAdd(out, v * (1.0f / ((float)NROWS * (float)NROWS)));
    }
}

// ---------- fallback: D-GEMM with fused loss epilogue (ws too small) ----------
__global__ __launch_bounds__(256) void dloss_kernel(
    const ushort_t* __restrict__ Inrm, const ushort_t* __restrict__ Tnrm,
    const float2* __restrict__ params2, const int* __restrict__ instr,
    const unsigned char* __restrict__ simb, float* __restrict__ out) {
    __shared__ __align__(16) ushort_t Ta[2][128 * 64];
    __shared__ __align__(16) ushort_t Tb[2][128 * 64];
    const int b2 = blockIdx.x;
    const int ti = b2 >> 5, tj = b2 & 31;
    const int wave = threadIdx.x >> 6, lane = threadIdx.x & 63;
    const int wr = wave >> 1, wc = wave & 1;
    const ushort_t* gA = Inrm + (size_t)(ti * 128) * DIM;
    const ushort_t* gB = Tnrm + (size_t)(tj * 128) * DIM;

    floatx4 acc[4][4];
#pragma unroll
    for (int m = 0; m < 4; m++)
#pragma unroll
        for (int n = 0; n < 4; n++) acc[m][n] = (floatx4){0.f, 0.f, 0.f, 0.f};

    stage_tile(gA, Ta[0], wave, lane);
    stage_tile(gB, Tb[0], wave, lane);
    __syncthreads();
#pragma unroll
    for (int t = 0; t < NKS; t++) {
        if (t + 1 < NKS) {
            stage_tile(gA + (t + 1) * 64, Ta[(t + 1) & 1], wave, lane);
            stage_tile(gB + (t + 1) * 64, Tb[(t + 1) & 1], wave, lane);
        }
#pragma unroll
        for (int kk = 0; kk < 2; kk++) {
            short8 a[4], b[4];
#pragma unroll
            for (int m = 0; m < 4; m++) a[m] = read_frag(Ta[t & 1], wr * 4 + m, kk, lane);
#pragma unroll
            for (int n = 0; n < 4; n++) b[n] = read_frag(Tb[t & 1], wc * 4 + n, kk, lane);
#pragma unroll
            for (int m = 0; m < 4; m++)
#pragma unroll
                for (int n = 0; n < 4; n++)
                    acc[m][n] = __builtin_amdgcn_mfma_f32_16x16x32_bf16(a[m], b[n], acc[m][n], 0, 0, 0);
        }
        __syncthreads();
    }

    const unsigned char* spb = simb + ((size_t)((ti * NT + tj) * 4 + wave)) * 4096;
    const int rbase0 = ti * 128 + wr * 64;
    const int cbase0 = tj * 128 + wc * 64;
    int ic4[4];
#pragma unroll
    for (int n = 0; n < 4; n++) ic4[n] = instr[cbase0 + n * 16 + (lane & 15)];
    float lsum = 0.f;
#pragma unroll
    for (int m = 0; m < 4; m++) {
        uintx4 q = *reinterpret_cast<const uintx4*>(spb + m * 1024 + lane * 16);
        int rb = rbase0 + m * 16 + (lane >> 4) * 4;
#pragma unroll
        for (int reg = 0; reg < 4; reg++) {
            int row_g = rb + reg;
            float2 pp = params2[row_g];
            int   ir  = instr[row_g];
#pragma unroll
            for (int n = 0; n < 4; n++) {
                int col_g = cbase0 + n * 16 + (lane & 15);
                float simv = fp82f((q[n] >> (8 * reg)) & 0xFFu);
                float cosv = acc[m][n][reg];
                float w = (simv - pp.x) * pp.y;
                bool aligned = (ir == ic4[n]) || (row_g == col_g);
                lsum += aligned ? (1.0f - cosv) : fmaxf(0.0f, cosv - w);
            }
        }
    }
#pragma unroll
    for (int s = 1; s < 64; s <<= 1) lsum += __shfl_xor(lsum, s);
    if (lane == 0)
        atomicAdd(out, lsum * (1.0f / ((float)NROWS * (float)NROWS)));
}

// ---------- launch ----------
extern "C" void kernel_launch(void* const* d_in, const int* in_sizes, int n_in,
                              void* d_out, int out_size, void* d_ws, size_t ws_size,
                              hipStream_t stream) {
    const float* img = (const float*)d_in[0];
    const float* txt = (const float*)d_in[1];
    const int* instr = (const int*)d_in[2];
    float* out = (float*)d_out;

    char* ws = (char*)d_ws;
    const size_t MAT = (size_t)NROWS * DIM * 2;                     // 4 MB
    ushort_t* Traw = (ushort_t*)ws;
    ushort_t* Inrm = (ushort_t*)(ws + MAT);
    ushort_t* Tnrm = (ushort_t*)(ws + 2 * MAT);
    unsigned* mn_u = (unsigned*)(ws + 3 * MAT);                     // 16 KB
    unsigned* mx_u = mn_u + NROWS;                                  // 16 KB
    float2* params2 = (float2*)(mx_u + NROWS);                      // 32 KB (fallback)
    unsigned char* simb = (unsigned char*)(params2 + NROWS);        // 16 MB (fp8)
    unsigned char* dotb = simb + (size_t)NROWS * NROWS;             // 16 MB (fp8)
    const size_t need = 3 * MAT + (size_t)NROWS * 16
                      + (size_t)NROWS * NROWS * 2;                  // ~44 MB

    prep_kernel<<<NROWS / 4, 256, 0, stream>>>(img, txt, Inrm, Traw, Tnrm,
                                               mn_u, mx_u, out);
    if (ws_size >= need) {
        gemm_kernel<0><<<NS + NT * NT, 256, 0, stream>>>(Traw, Inrm, Tnrm,
                                                         mn_u, mx_u, simb, dotb);
        loss_kernel<<<512, 256, 0, stream>>>(simb, dotb, mn_u, mx_u, instr, out);
    } else {
        gemm_kernel<1><<<NT * NT, 256, 0, stream>>>(Traw, Inrm, Tnrm,
                                                    mn_u, mx_u, simb, dotb);
        params_kernel<<<NROWS / 256, 256, 0, stream>>>(mn_u, mx_u, params2);
        dloss_kernel<<<NT * NT, 256, 0, stream>>>(Inrm, Tnrm, params2, instr, simb, out);
    }
}

// Round 21
// 68.238 us; speedup vs baseline: 1.0631x; 1.0631x over previous
//
#include <hip/hip_runtime.h>
#include <stdint.h>

#define NROWS 4096
#define DIM   512
#define EPS_W   1e-6f
#define NT    (NROWS / 128)        // 32 tiles per dim
#define NKS   (DIM / 64)           // 8 K-steps
#define NS    528                  // upper-triangle S tiles: 32*33/2

typedef unsigned short ushort_t;
typedef __attribute__((ext_vector_type(8))) short   short8;
typedef __attribute__((ext_vector_type(8))) unsigned short ushort8;
typedef __attribute__((ext_vector_type(4))) float   floatx4;
typedef __attribute__((ext_vector_type(4))) unsigned int uintx4;

// ---------- helpers ----------
__device__ inline ushort_t f2bf(float x) {            // RNE float->bf16
    unsigned u = __float_as_uint(x);
    unsigned r = (u + 0x7FFFu + ((u >> 16) & 1u)) >> 16;
    return (ushort_t)r;
}
__device__ inline float bf2f(ushort_t u) {
    return __uint_as_float(((unsigned)u) << 16);
}
// manual fp8 e4m3fn (OCP): RNE encode w/ clamp to 448, flush |x|<2^-6 to 0.
// sim only feeds w=(sim-mn)*winv; diag (saturated) pairs are always 'aligned'.
__device__ inline unsigned f2fp8(float x) {
    unsigned s = (__float_as_uint(x) >> 24) & 0x80u;
    float ax = fminf(fabsf(x), 448.0f);
    unsigned u = __float_as_uint(ax);
    unsigned r = u + 0x7FFFFu + ((u >> 20) & 1u);     // RNE at 3-bit mantissa
    unsigned b = s | (((r >> 23) - 120u) << 3) | ((r >> 20) & 7u);
    return (ax >= 0.015625f) ? b : s;                 // flush tiny to +-0
}
__device__ inline float fp82f(unsigned b) {
    unsigned em = b & 0x7Fu;
    float v = __uint_as_float(((b & 0x80u) << 24) | ((em << 20) + 0x3C000000u));
    return (em >= 8u) ? v : 0.0f;                     // encoder emits no subnormals
}
__device__ inline unsigned fmap(float f) {
    unsigned u = __float_as_uint(f);
    return (u & 0x80000000u) ? ~u : (u | 0x80000000u);
}
__device__ inline float funmap(unsigned u) {
    return __uint_as_float((u & 0x80000000u) ? (u & 0x7fffffffu) : ~u);
}

__device__ inline void gload_lds16(const void* g, void* l) {
    auto* gp = reinterpret_cast<const __attribute__((address_space(1))) unsigned int*>(
        reinterpret_cast<uintptr_t>(g));
    auto* lp = reinterpret_cast<__attribute__((address_space(3))) unsigned int*>(
        reinterpret_cast<uintptr_t>(l));
    __builtin_amdgcn_global_load_lds(gp, lp, 16, 0, 0);
}

// R1-verified 128x64 staging (0 bank conflicts). LDS[r][c_phys] holds logical
// chunk c_phys ^ (r&7) (chunk = 16B = 8 bf16).
__device__ inline void stage_tile(const ushort_t* __restrict__ gbase,
                                  ushort_t* lds, int wave, int lane) {
#pragma unroll
    for (int q = 0; q < 4; q++) {
        int row0 = wave * 32 + q * 8;
        int lrow = row0 + (lane >> 3);
        int src_chunk = (lane & 7) ^ (lane >> 3);
        const ushort_t* g = gbase + (size_t)lrow * DIM + src_chunk * 8;
        gload_lds16(g, lds + row0 * 64);
    }
}
__device__ inline short8 read_frag(const ushort_t* tile, int frag_row, int kk, int lane) {
    int r = frag_row * 16 + (lane & 15);
    int c = (kk * 4 + (lane >> 4)) ^ (lane & 7);
    return *reinterpret_cast<const short8*>(tile + r * 64 + c * 8);
}

// ---------- kernel 1: convert (raw T + normalized I,T) + init + out=0 ----------
__global__ __launch_bounds__(256) void prep_kernel(
    const float* __restrict__ img, const float* __restrict__ txt,
    ushort_t* __restrict__ Inrm, ushort_t* __restrict__ Traw,
    ushort_t* __restrict__ Tnrm,
    unsigned* __restrict__ mn_u, unsigned* __restrict__ mx_u,
    float* __restrict__ out) {
    const int wave = threadIdx.x >> 6, lane = threadIdx.x & 63;
    const int row = blockIdx.x * 4 + wave;
    const int col0 = lane * 8;
    if (blockIdx.x == 0 && threadIdx.x == 0) out[0] = 0.0f;  // replaces memset dispatch
    {
        const float4* p = reinterpret_cast<const float4*>(img + (size_t)row * DIM + col0);
        float4 a = p[0], b = p[1];
        float ss = a.x*a.x + a.y*a.y + a.z*a.z + a.w*a.w
                 + b.x*b.x + b.y*b.y + b.z*b.z + b.w*b.w;
#pragma unroll
        for (int s = 1; s < 64; s <<= 1) ss += __shfl_xor(ss, s);
        float rin = rsqrtf(ss);
        ushort8 o;
        o[0]=f2bf(a.x*rin); o[1]=f2bf(a.y*rin); o[2]=f2bf(a.z*rin); o[3]=f2bf(a.w*rin);
        o[4]=f2bf(b.x*rin); o[5]=f2bf(b.y*rin); o[6]=f2bf(b.z*rin); o[7]=f2bf(b.w*rin);
        *reinterpret_cast<ushort8*>(Inrm + (size_t)row * DIM + col0) = o;
    }
    {
        const float4* p = reinterpret_cast<const float4*>(txt + (size_t)row * DIM + col0);
        float4 a = p[0], b = p[1];
        float ss = a.x*a.x + a.y*a.y + a.z*a.z + a.w*a.w
                 + b.x*b.x + b.y*b.y + b.z*b.z + b.w*b.w;
#pragma unroll
        for (int s = 1; s < 64; s <<= 1) ss += __shfl_xor(ss, s);
        float rtn = rsqrtf(ss);
        ushort8 r8, n8;
        r8[0]=f2bf(a.x); r8[1]=f2bf(a.y); r8[2]=f2bf(a.z); r8[3]=f2bf(a.w);
        r8[4]=f2bf(b.x); r8[5]=f2bf(b.y); r8[6]=f2bf(b.z); r8[7]=f2bf(b.w);
        n8[0]=f2bf(a.x*rtn); n8[1]=f2bf(a.y*rtn); n8[2]=f2bf(a.z*rtn); n8[3]=f2bf(a.w*rtn);
        n8[4]=f2bf(b.x*rtn); n8[5]=f2bf(b.y*rtn); n8[6]=f2bf(b.z*rtn); n8[7]=f2bf(b.w*rtn);
        *reinterpret_cast<ushort8*>(Traw + (size_t)row * DIM + col0) = r8;
        *reinterpret_cast<ushort8*>(Tnrm + (size_t)row * DIM + col0) = n8;
    }
    if (lane == 0) { mn_u[row] = 0xFFFFFFFFu; mx_u[row] = 0u; }
}

// ---------- kernel 2: fused S/D GEMM, 2-phase dbuf + S-symmetry; sim in fp8 ----------
// Grid (SONLY=0): NS + 1024. bid < NS -> S tile (upper tri, ti <= tj); else D.
// S store: fp8 e4m3, wave-slot = 4 KB, chunk f=m holds uint n (4 regs/bytes).
// D store: bf16 chunk-major (wave-slot 8 KB) -- fp8 D-encode refuted (R20: +4.6us VALU).
template <int SONLY>
__global__ __launch_bounds__(256) void gemm_kernel(
    const ushort_t* __restrict__ Traw, const ushort_t* __restrict__ Inrm,
    const ushort_t* __restrict__ Tnrm,
    unsigned* __restrict__ mn_u, unsigned* __restrict__ mx_u,
    unsigned char* __restrict__ simb, ushort_t* __restrict__ dotbuf) {
    __shared__ __align__(16) ushort_t LB[32768];     // 64 KB: Ta0|Ta1|Tb0|Tb1, reused
    ushort_t* TaB = LB;
    ushort_t* TbB = LB + 16384;
    int type, ti, tj;
    if (SONLY) {
        type = 0; ti = (int)blockIdx.x >> 5; tj = (int)blockIdx.x & 31;
    } else {
        int bid = (int)blockIdx.x;
        if (bid < NS) {                              // S: upper-triangle decode
            type = 0;
            int u = bid;
            int t = (int)(32.5f - sqrtf(32.5f * 32.5f - 2.0f * (float)u));
            int off = 32 * t - (t * (t - 1)) / 2;
            if (off > u) { t--; off = 32 * t - (t * (t - 1)) / 2; }
            else if (off + (32 - t) <= u) { off += (32 - t); t++; }
            ti = t; tj = t + (u - off);
        } else {
            type = 1; int v = bid - NS; ti = v >> 5; tj = v & 31;
        }
    }
    const int wave = threadIdx.x >> 6, lane = threadIdx.x & 63;
    const int wr = wave >> 1, wc = wave & 1;
    const ushort_t* gA = (type ? Inrm : Traw) + (size_t)(ti * 128) * DIM;
    const ushort_t* gB = (type ? Tnrm : Traw) + (size_t)(tj * 128) * DIM;

    floatx4 acc[4][4];
#pragma unroll
    for (int m = 0; m < 4; m++)
#pragma unroll
        for (int n = 0; n < 4; n++) acc[m][n] = (floatx4){0.f, 0.f, 0.f, 0.f};

    // 2-phase: issue next-step stage FIRST, compute current, one sync per step
    stage_tile(gA, TaB, wave, lane);
    stage_tile(gB, TbB, wave, lane);
    __syncthreads();
#pragma unroll
    for (int t = 0; t < NKS; t++) {
        if (t + 1 < NKS) {
            stage_tile(gA + (t + 1) * 64, TaB + ((t + 1) & 1) * 8192, wave, lane);
            stage_tile(gB + (t + 1) * 64, TbB + ((t + 1) & 1) * 8192, wave, lane);
        }
#pragma unroll
        for (int kk = 0; kk < 2; kk++) {
            short8 a[4], b[4];
#pragma unroll
            for (int m = 0; m < 4; m++) a[m] = read_frag(TaB + (t & 1) * 8192, wr * 4 + m, kk, lane);
#pragma unroll
            for (int n = 0; n < 4; n++) b[n] = read_frag(TbB + (t & 1) * 8192, wc * 4 + n, kk, lane);
#pragma unroll
            for (int m = 0; m < 4; m++)
#pragma unroll
                for (int n = 0; n < 4; n++)
                    acc[m][n] = __builtin_amdgcn_mfma_f32_16x16x32_bf16(a[m], b[n], acc[m][n], 0, 0, 0);
        }
        __syncthreads();
    }

    if (type == 0) {
        // row-axis min/max (fp32-exact, unaffected by fp8 sim store)
#pragma unroll
        for (int m = 0; m < 4; m++) {
#pragma unroll
            for (int reg = 0; reg < 4; reg++) {
                float vmin = acc[m][0][reg], vmax = acc[m][0][reg];
#pragma unroll
                for (int n = 1; n < 4; n++) {
                    vmin = fminf(vmin, acc[m][n][reg]);
                    vmax = fmaxf(vmax, acc[m][n][reg]);
                }
#pragma unroll
                for (int s = 1; s < 16; s <<= 1) {
                    vmin = fminf(vmin, __shfl_xor(vmin, s));
                    vmax = fmaxf(vmax, __shfl_xor(vmax, s));
                }
                if ((lane & 15) == 0) {
                    int row_g = ti * 128 + wr * 64 + m * 16 + (lane >> 4) * 4 + reg;
                    atomicMin(&mn_u[row_g], fmap(vmin));
                    atomicMax(&mx_u[row_g], fmap(vmax));
                }
            }
        }
        if (!SONLY && ti != tj) {
            // col-axis min/max -> rows of tj block by symmetry
#pragma unroll
            for (int n = 0; n < 4; n++) {
                float cmin = acc[0][n][0], cmax = acc[0][n][0];
#pragma unroll
                for (int m = 0; m < 4; m++)
#pragma unroll
                    for (int reg = 0; reg < 4; reg++) {
                        float v = acc[m][n][reg];
                        cmin = fminf(cmin, v); cmax = fmaxf(cmax, v);
                    }
                cmin = fminf(cmin, __shfl_xor(cmin, 16));
                cmax = fmaxf(cmax, __shfl_xor(cmax, 16));
                cmin = fminf(cmin, __shfl_xor(cmin, 32));
                cmax = fmaxf(cmax, __shfl_xor(cmax, 32));
                if ((lane >> 4) == 0) {
                    int row_g = tj * 128 + wc * 64 + n * 16 + lane;
                    atomicMin(&mn_u[row_g], fmap(cmin));
                    atomicMax(&mx_u[row_g], fmap(cmax));
                }
            }
        }
        // packed fp8 sim store at (ti,tj): chunk f=m, uint n = regs 0..3 (bytes)
        unsigned char* spb = simb + ((size_t)((ti * NT + tj) * 4 + wave)) * 4096;
#pragma unroll
        for (int f = 0; f < 4; f++) {
            uintx4 q;
#pragma unroll
            for (int n = 0; n < 4; n++)
                q[n] = f2fp8(acc[f][n][0])
                     | (f2fp8(acc[f][n][1]) << 8)
                     | (f2fp8(acc[f][n][2]) << 16)
                     | (f2fp8(acc[f][n][3]) << 24);
            *reinterpret_cast<uintx4*>(spb + f * 1024 + lane * 16) = q;
        }
        // transposed fp8 store at (tj,ti) via byte LDS bounce
        if (!SONLY && ti != tj) {
            unsigned char* LBb = reinterpret_cast<unsigned char*>(LB);
            const int rb0 = wr * 64, cb0 = wc * 64;
            const int l4 = lane >> 4, l15 = lane & 15;
#pragma unroll
            for (int m = 0; m < 4; m++)
#pragma unroll
                for (int n = 0; n < 4; n++)
#pragma unroll
                    for (int reg = 0; reg < 4; reg++)
                        LBb[(rb0 + m * 16 + l4 * 4 + reg) * 132 + (cb0 + n * 16 + l15)]
                            = (unsigned char)f2fp8(acc[m][n][reg]);
            __syncthreads();
            unsigned char* sp2 = simb + ((size_t)((tj * NT + ti) * 4 + wave)) * 4096;
#pragma unroll
            for (int f2 = 0; f2 < 4; f2++) {
                int row2b = (wave >> 1) * 64 + f2 * 16 + l4 * 4;       // mult of 4
                uintx4 q;
#pragma unroll
                for (int n2 = 0; n2 < 4; n2++) {
                    int col2 = (wave & 1) * 64 + n2 * 16 + l15;
                    q[n2] = *reinterpret_cast<const unsigned*>(&LBb[col2 * 132 + row2b]);
                }
                *reinterpret_cast<uintx4*>(sp2 + f2 * 1024 + lane * 16) = q;
            }
        }
    } else {
        // D: packed bf16 cos store, chunk-major (wave-slot 8 KB)
        ushort_t* sp = dotbuf + ((size_t)((ti * NT + tj) * 4 + wave)) * 4096;
#pragma unroll
        for (int c = 0; c < 8; c++) {
            int m = c >> 1, n0 = (c & 1) * 2;
            ushort8 o;
            o[0] = f2bf(acc[m][n0][0]);     o[1] = f2bf(acc[m][n0][1]);
            o[2] = f2bf(acc[m][n0][2]);     o[3] = f2bf(acc[m][n0][3]);
            o[4] = f2bf(acc[m][n0 + 1][0]); o[5] = f2bf(acc[m][n0 + 1][1]);
            o[6] = f2bf(acc[m][n0 + 1][2]); o[7] = f2bf(acc[m][n0 + 1][3]);
            *reinterpret_cast<ushort8*>(sp + c * 512 + lane * 8) = o;
        }
    }
}

// ---------- kernel 3 (fallback path only): per-row params ----------
__global__ __launch_bounds__(256) void params_kernel(
    const unsigned* __restrict__ mn_u, const unsigned* __restrict__ mx_u,
    float2* __restrict__ params2) {
    int i = blockIdx.x * 256 + threadIdx.x;
    float mn = funmap(mn_u[i]), mx = funmap(mx_u[i]);
    params2[i] = make_float2(mn, 1.0f / (mx - mn + EPS_W));
}

// ---------- kernel 4: streaming loss; fp8 sim + bf16 dot, params in LDS ----------
// lane-chunk16 id g = t + k*2^17, k in [0,8): wslot = g>>8, f = (g>>6)&3,
// ln = g&63. k-invariant: f, ln, wave, tj; ti = ti0 + 4k. Per k: one 16B fp8
// sim load (16 pairs) + two 16B bf16 dot loads. 48 MB total.
__global__ __launch_bounds__(256) void loss_kernel(
    const unsigned char* __restrict__ simb, const ushort_t* __restrict__ dotbuf,
    const unsigned* __restrict__ mn_u, const unsigned* __restrict__ mx_u,
    const int* __restrict__ instr, float* __restrict__ out) {
    __shared__ __align__(16) float2 P[NROWS];            // 32 KB
    __shared__ float red[4];
    const int t = blockIdx.x * 256 + threadIdx.x;        // 0..131071
    const int rem = t & 255;
    const int f = rem >> 6, ln = rem & 63;
    const int wslot0 = t >> 8;                           // + 512k
    const int wv0 = wslot0 & 3;
    const int tile0 = wslot0 >> 2;                       // + 128k
    const int tj = tile0 & 31;
    const int ti0 = tile0 >> 5;                          // ti = ti0 + 4k

    uintx4 sv[8]; ushort8 dv0[8], dv1[8];
#pragma unroll
    for (int k = 0; k < 8; k++) {
        size_t ws = (size_t)(wslot0 + k * 512);
        sv[k] = __builtin_nontemporal_load(
            reinterpret_cast<const uintx4*>(simb + ws * 4096 + f * 1024 + ln * 16));
        dv0[k] = __builtin_nontemporal_load(
            reinterpret_cast<const ushort8*>(dotbuf + ws * 4096 + (2 * f) * 512 + ln * 8));
        dv1[k] = __builtin_nontemporal_load(
            reinterpret_cast<const ushort8*>(dotbuf + ws * 4096 + (2 * f + 1) * 512 + ln * 8));
    }
    // params into LDS (16 rows/thread, coalesced; divides hide under loads)
#pragma unroll
    for (int q = 0; q < 16; q++) {
        int i = threadIdx.x + q * 256;
        float mn = funmap(mn_u[i]), mx = funmap(mx_u[i]);
        P[i] = make_float2(mn, 1.0f / (mx - mn + EPS_W));
    }
    __syncthreads();
    const int rb_lo = (wv0 >> 1) * 64 + f * 16 + (ln >> 4) * 4;
    const int cb = tj * 128 + (wv0 & 1) * 64 + (ln & 15);
    int icn[4], coln[4];
#pragma unroll
    for (int n = 0; n < 4; n++) { coln[n] = cb + n * 16; icn[n] = instr[coln[n]]; }

    float lsum = 0.f;
#pragma unroll
    for (int k = 0; k < 8; k++) {
        int rb = (ti0 + 4 * k) * 128 + rb_lo;            // %4 == 0
        float4 pA = *reinterpret_cast<const float4*>(&P[rb]);      // mn0,w0,mn1,w1
        float4 pB = *reinterpret_cast<const float4*>(&P[rb + 2]);  // mn2,w2,mn3,w3
        int4  ir4 = *reinterpret_cast<const int4*>(instr + rb);
#pragma unroll
        for (int n = 0; n < 4; n++) {
            unsigned q = sv[k][n];
            const int base = (n & 1) * 4;
#pragma unroll
            for (int reg = 0; reg < 4; reg++) {
                float mn, wvv; int ir;
                if (reg == 0)      { mn = pA.x; wvv = pA.y; ir = ir4.x; }
                else if (reg == 1) { mn = pA.z; wvv = pA.w; ir = ir4.y; }
                else if (reg == 2) { mn = pB.x; wvv = pB.y; ir = ir4.z; }
                else               { mn = pB.z; wvv = pB.w; ir = ir4.w; }
                float simv = fp82f((q >> (8 * reg)) & 0xFFu);
                float cosv = bf2f((n < 2) ? dv0[k][base + reg] : dv1[k][base + reg]);
                float w = (simv - mn) * wvv;
                bool aligned = (ir == icn[n]) || (rb + reg == coln[n]);
                lsum += aligned ? (1.0f - cosv) : fmaxf(0.0f, cosv - w);
            }
        }
    }
#pragma unroll
    for (int s = 1; s < 64; s <<= 1) lsum += __shfl_xor(lsum, s);
    const int wave = threadIdx.x >> 6, lane = threadIdx.x & 63;
    if (lane == 0) red[wave] = lsum;
    __syncthreads();
    if (threadIdx.x == 0) {
        float v = red[0] + red[1] + red[2] + red[3];
        atomicAdd(out, v * (1.0f / ((float)NROWS * (float)NROWS)));
    }
}

// ---------- fallback: D-GEMM with fused loss epilogue (ws too small) ----------
__global__ __launch_bounds__(256) void dloss_kernel(
    const ushort_t* __restrict__ Inrm, const ushort_t* __restrict__ Tnrm,
    const float2* __restrict__ params2, const int* __restrict__ instr,
    const unsigned char* __restrict__ simb, float* __restrict__ out) {
    __shared__ __align__(16) ushort_t Ta[2][128 * 64];
    __shared__ __align__(16) ushort_t Tb[2][128 * 64];
    const int b2 = blockIdx.x;
    const int ti = b2 >> 5, tj = b2 & 31;
    const int wave = threadIdx.x >> 6, lane = threadIdx.x & 63;
    const int wr = wave >> 1, wc = wave & 1;
    const ushort_t* gA = Inrm + (size_t)(ti * 128) * DIM;
    const ushort_t* gB = Tnrm + (size_t)(tj * 128) * DIM;

    floatx4 acc[4][4];
#pragma unroll
    for (int m = 0; m < 4; m++)
#pragma unroll
        for (int n = 0; n < 4; n++) acc[m][n] = (floatx4){0.f, 0.f, 0.f, 0.f};

    stage_tile(gA, Ta[0], wave, lane);
    stage_tile(gB, Tb[0], wave, lane);
    __syncthreads();
#pragma unroll
    for (int t = 0; t < NKS; t++) {
        if (t + 1 < NKS) {
            stage_tile(gA + (t + 1) * 64, Ta[(t + 1) & 1], wave, lane);
            stage_tile(gB + (t + 1) * 64, Tb[(t + 1) & 1], wave, lane);
        }
#pragma unroll
        for (int kk = 0; kk < 2; kk++) {
            short8 a[4], b[4];
#pragma unroll
            for (int m = 0; m < 4; m++) a[m] = read_frag(Ta[t & 1], wr * 4 + m, kk, lane);
#pragma unroll
            for (int n = 0; n < 4; n++) b[n] = read_frag(Tb[t & 1], wc * 4 + n, kk, lane);
#pragma unroll
            for (int m = 0; m < 4; m++)
#pragma unroll
                for (int n = 0; n < 4; n++)
                    acc[m][n] = __builtin_amdgcn_mfma_f32_16x16x32_bf16(a[m], b[n], acc[m][n], 0, 0, 0);
        }
        __syncthreads();
    }

    const unsigned char* spb = simb + ((size_t)((ti * NT + tj) * 4 + wave)) * 4096;
    const int rbase0 = ti * 128 + wr * 64;
    const int cbase0 = tj * 128 + wc * 64;
    int ic4[4];
#pragma unroll
    for (int n = 0; n < 4; n++) ic4[n] = instr[cbase0 + n * 16 + (lane & 15)];
    float lsum = 0.f;
#pragma unroll
    for (int m = 0; m < 4; m++) {
        uintx4 q = *reinterpret_cast<const uintx4*>(spb + m * 1024 + lane * 16);
        int rb = rbase0 + m * 16 + (lane >> 4) * 4;
#pragma unroll
        for (int reg = 0; reg < 4; reg++) {
            int row_g = rb + reg;
            float2 pp = params2[row_g];
            int   ir  = instr[row_g];
#pragma unroll
            for (int n = 0; n < 4; n++) {
                int col_g = cbase0 + n * 16 + (lane & 15);
                float simv = fp82f((q[n] >> (8 * reg)) & 0xFFu);
                float cosv = acc[m][n][reg];
                float w = (simv - pp.x) * pp.y;
                bool aligned = (ir == ic4[n]) || (row_g == col_g);
                lsum += aligned ? (1.0f - cosv) : fmaxf(0.0f, cosv - w);
            }
        }
    }
#pragma unroll
    for (int s = 1; s < 64; s <<= 1) lsum += __shfl_xor(lsum, s);
    if (lane == 0)
        atomicAdd(out, lsum * (1.0f / ((float)NROWS * (float)NROWS)));
}

// ---------- launch ----------
extern "C" void kernel_launch(void* const* d_in, const int* in_sizes, int n_in,
                              void* d_out, int out_size, void* d_ws, size_t ws_size,
                              hipStream_t stream) {
    const float* img = (const float*)d_in[0];
    const float* txt = (const float*)d_in[1];
    const int* instr = (const int*)d_in[2];
    float* out = (float*)d_out;

    char* ws = (char*)d_ws;
    const size_t MAT = (size_t)NROWS * DIM * 2;                     // 4 MB
    ushort_t* Traw = (ushort_t*)ws;
    ushort_t* Inrm = (ushort_t*)(ws + MAT);
    ushort_t* Tnrm = (ushort_t*)(ws + 2 * MAT);
    unsigned* mn_u = (unsigned*)(ws + 3 * MAT);                     // 16 KB
    unsigned* mx_u = mn_u + NROWS;                                  // 16 KB
    float2* params2 = (float2*)(mx_u + NROWS);                      // 32 KB (fallback)
    unsigned char* simb = (unsigned char*)(params2 + NROWS);        // 16 MB (fp8)
    ushort_t* dotbuf = (ushort_t*)(simb + (size_t)NROWS * NROWS);   // 32 MB (bf16)
    const size_t need = 3 * MAT + (size_t)NROWS * 16
                      + (size_t)NROWS * NROWS * 3;                  // ~60 MB

    prep_kernel<<<NROWS / 4, 256, 0, stream>>>(img, txt, Inrm, Traw, Tnrm,
                                               mn_u, mx_u, out);
    if (ws_size >= need) {
        gemm_kernel<0><<<NS + NT * NT, 256, 0, stream>>>(Traw, Inrm, Tnrm,
                                                         mn_u, mx_u, simb, dotbuf);
        loss_kernel<<<512, 256, 0, stream>>>(simb, dotbuf, mn_u, mx_u, instr, out);
    } else {
        gemm_kernel<1><<<NT * NT, 256, 0, stream>>>(Traw, Inrm, Tnrm,
                                                    mn_u, mx_u, simb, dotbuf);
        params_kernel<<<NROWS / 256, 256, 0, stream>>>(mn_u, mx_u, params2);
        dloss_kernel<<<NT * NT, 256, 0, stream>>>(Inrm, Tnrm, params2, instr, simb, out);
    }
}